// Round 2
// baseline (279.240 us; speedup 1.0000x reference)
//
#include <hip/hip_runtime.h>
#include <hip/hip_cooperative_groups.h>

namespace cg = cooperative_groups;

// Problem constants (from reference)
#define NN     1024      // nodes
#define INDIM  64
#define EREAL  16384
#define HD     64        // H*D = 8*8
#define NBLK   512
#define NTHR   256

// GAMMA = 0.1 ; C = GAMMA/(1+GAMMA) ; scale = sqrt(D)=sqrt(8)
constexpr float C_BASE    = 0.1f / 1.1f;
constexpr float INV_1P1   = 1.0f / 1.1f;
constexpr float INV_SCALE = 0.35355339059327373f;  // 1/sqrt(8)

// broadcast lane `lane`'s value to all lanes as a wave-uniform (SGPR) float
__device__ __forceinline__ float bcast(float v, int lane) {
    return __uint_as_float(__builtin_amdgcn_readlane(__float_as_uint(v), lane));
}

// One cooperative kernel, 512 blocks x 256 threads (2 blocks/CU -> co-resident).
// Phase 0: zero accumulators/winner (blocks 256..511) + node projections (blocks 0..255)
// Phase 1: dedup winner atomicMax (first 16384 threads) + Vh column-sum partials (last 16 blocks)
// Phase 2: per-edge delta + scatter accumulate (8 edges per wave)
// Phase 3: finalize out = (C*(S - Vh) + outacc) / (C*(N-1) + zacc + 1e-6)
__global__ __launch_bounds__(NTHR, 2)
void fused_kernel(const float* __restrict__ h,
                  const float* __restrict__ e,
                  const float* __restrict__ WQ,
                  const float* __restrict__ WK,
                  const float* __restrict__ WE,
                  const float* __restrict__ WV,
                  const int*   __restrict__ src,
                  const int*   __restrict__ dst,
                  float* __restrict__ Qh,
                  float* __restrict__ Kh,
                  float* __restrict__ Vh,
                  float* __restrict__ outacc,   // contiguous with zacc, Spart!
                  float* __restrict__ zacc,
                  float* __restrict__ Spart,
                  int*   __restrict__ winner,
                  float* __restrict__ out)
{
    cg::grid_group grid = cg::this_grid();
    const int tid  = threadIdx.x;
    const int bid  = blockIdx.x;
    const int gtid = bid * NTHR + tid;
    __shared__ float lds_buf[4][HD];

    // ---------------- Phase 0: zero + proj ----------------
    if (bid >= 256) {
        const int z = (bid - 256) * NTHR + tid;          // 0..65535
        const float4 zero4 = make_float4(0.f, 0.f, 0.f, 0.f);
        // region A: outacc(65536f) + zacc(8192f) + Spart(1024f) = 18688 float4 (contiguous)
        float4* regA = (float4*)outacc;
        if (z < 18688) regA[z] = zero4;
        // region B: winner = 1M ints = 262144 float4
        float4* regB = (float4*)winner;
#pragma unroll
        for (int i = 0; i < 4; ++i) regB[z + i * 65536] = zero4;
    } else {
        // proj: rows bid*4 .. bid*4+3, one thread per (row, col)
        const int g = tid >> 6, c = tid & 63;
        const int row = bid * 4 + g;
        lds_buf[g][c] = h[row * INDIM + c];
        __syncthreads();
        float q = 0.f, k = 0.f, v = 0.f;
#pragma unroll
        for (int r = 0; r < INDIM; ++r) {
            const float hv = lds_buf[g][r];
            q = fmaf(hv, WQ[r * HD + c], q);
            k = fmaf(hv, WK[r * HD + c], k);
            v = fmaf(hv, WV[r * HD + c], v);
        }
        Qh[row * HD + c] = q;
        Kh[row * HD + c] = k;
        Vh[row * HD + c] = v;
    }
    grid.sync();

    // ---------------- Phase 1: winner + colsum partials ----------------
    if (gtid < EREAL) {
        atomicMax(&winner[src[gtid] * NN + dst[gtid]], gtid + 1);
    }
    if (bid >= NBLK - 16) {
        const int p = bid - (NBLK - 16);                 // 0..15
        const int g = tid >> 6, c = tid & 63;
        float s = 0.f;
        const int j0 = p * 64 + g * 16;
        for (int j = j0; j < j0 + 16; ++j) s += Vh[j * HD + c];
        lds_buf[g][c] = s;
        __syncthreads();
        if (g == 0)
            Spart[p * HD + c] = lds_buf[0][c] + lds_buf[1][c] + lds_buf[2][c] + lds_buf[3][c];
    }
    grid.sync();

    // ---------------- Phase 2: edges (8 per wave) ----------------
    {
        const int wave = gtid >> 6;                      // 0..2047
        const int t = tid & 63;                          // lane = h*8+d
        const int k0 = wave * 8;
        float ev[8];
#pragma unroll
        for (int i = 0; i < 8; ++i) ev[i] = e[(k0 + i) * INDIM + t];
        float acc[8] = {0.f, 0.f, 0.f, 0.f, 0.f, 0.f, 0.f, 0.f};
        // Eh[k,t] = sum_r e[k,r]*WE[r,t]; one WE load feeds 8 edges via readlane broadcast
#pragma unroll
        for (int r = 0; r < INDIM; ++r) {
            const float w = WE[r * HD + t];
#pragma unroll
            for (int i = 0; i < 8; ++i)
                acc[i] = fmaf(bcast(ev[i], r), w, acc[i]);
        }
#pragma unroll
        for (int i = 0; i < 8; ++i) {
            const int k = k0 + i;
            const int s = src[k];
            const int d = dst[k];
            // wave-uniform skip: duplicate losers (last-set-wins) and self-loops
            if (winner[s * NN + d] != k + 1 || s == d) continue;
            float term = Kh[s * HD + t] * Qh[d * HD + t] * acc[i];
            term += __shfl_xor(term, 1, 64);
            term += __shfl_xor(term, 2, 64);
            term += __shfl_xor(term, 4, 64);
            const float wr    = fminf(fmaxf(term * INV_SCALE, -5.f), 5.f);
            const float delta = __expf(wr) * INV_1P1 - C_BASE;
            atomicAdd(&outacc[d * HD + t], delta * Vh[s * HD + t]);
            if ((t & 7) == 0) atomicAdd(&zacc[d * 8 + (t >> 3)], delta);
        }
    }
    grid.sync();

    // ---------------- Phase 3: finalize ----------------
    if (bid < 256) {
        const int idx = gtid;                            // 0..65535
        const int j = idx >> 6, t = idx & 63;
        float S = 0.f;
#pragma unroll
        for (int p = 0; p < 16; ++p) S += Spart[p * HD + t];
        const float z = C_BASE * 1023.f + zacc[j * 8 + (t >> 3)] + 1e-6f;
        out[idx] = fmaf(C_BASE, S - Vh[idx], outacc[idx]) / z;
    }
}

extern "C" void kernel_launch(void* const* d_in, const int* in_sizes, int n_in,
                              void* d_out, int out_size, void* d_ws, size_t ws_size,
                              hipStream_t stream) {
    const float* h  = (const float*)d_in[0];
    const float* e  = (const float*)d_in[1];
    const float* WQ = (const float*)d_in[2];
    const float* WK = (const float*)d_in[3];
    const float* WE = (const float*)d_in[4];
    // d_in[5..7] = WQ2, WK2, WE2 — provably unused: fake weights are overwritten
    // at every real-edge position and equal GAMMA/(1+GAMMA) elsewhere.
    const float* WV = (const float*)d_in[8];
    const int* src  = (const int*)d_in[9];
    const int* dst  = (const int*)d_in[10];
    float* out = (float*)d_out;

    char* ws = (char*)d_ws;
    float* Qh     = (float*)(ws + (0    << 10));   // 256 KB
    float* Kh     = (float*)(ws + (256  << 10));   // 256 KB
    float* Vh     = (float*)(ws + (512  << 10));   // 256 KB
    float* outacc = (float*)(ws + (768  << 10));   // 256 KB  -- zeroed in-kernel
    float* zacc   = (float*)(ws + (1024 << 10));   // 32 KB   -- contiguous with outacc
    float* Spart  = (float*)(ws + (1056 << 10));   // 4 KB    -- contiguous with zacc
    int*   winner = (int*)  (ws + (2    << 20));   // 4 MB    -- zeroed in-kernel

    void* args[] = {(void*)&h, (void*)&e, (void*)&WQ, (void*)&WK, (void*)&WE,
                    (void*)&WV, (void*)&src, (void*)&dst,
                    (void*)&Qh, (void*)&Kh, (void*)&Vh,
                    (void*)&outacc, (void*)&zacc, (void*)&Spart,
                    (void*)&winner, (void*)&out};
    hipLaunchCooperativeKernel((const void*)fused_kernel, dim3(NBLK), dim3(NTHR),
                               args, 0, stream);
}

// Round 3
// 100.646 us; speedup vs baseline: 2.7745x; 2.7745x over previous
//
#include <hip/hip_runtime.h>

// Problem constants (from reference)
#define NN     1024      // nodes
#define INDIM  64
#define EREAL  16384
#define HD     64        // H*D = 8*8

// GAMMA = 0.1 ; C = GAMMA/(1+GAMMA) ; scale = sqrt(D)=sqrt(8)
constexpr float C_BASE    = 0.1f / 1.1f;
constexpr float INV_1P1   = 1.0f / 1.1f;
constexpr float INV_SCALE = 0.35355339059327373f;  // 1/sqrt(8)

// broadcast lane `lane`'s value to all lanes as a wave-uniform (SGPR) float
__device__ __forceinline__ float bcast(float v, int lane) {
    return __uint_as_float(__builtin_amdgcn_readlane(__float_as_uint(v), lane));
}

// ---- Kernel A: proj (blocks 0..255) | winner atomicMax (256..319) | h column-sum partials (320..335)
// All three are independent; winner ordering only needs the preceding memset.
__global__ __launch_bounds__(256)
void prep_kernel(const float* __restrict__ h,
                 const float* __restrict__ WQ,
                 const float* __restrict__ WK,
                 const float* __restrict__ WV,
                 const int*   __restrict__ src,
                 const int*   __restrict__ dst,
                 float* __restrict__ Qh,
                 float* __restrict__ Kh,
                 float* __restrict__ Vh,
                 float* __restrict__ Spart,   // [16][INDIM] partial column sums of h
                 int*   __restrict__ winner)
{
    const int tid = threadIdx.x;
    const int bid = blockIdx.x;
    const int g = tid >> 6, c = tid & 63;
    __shared__ float lds_buf[4][64];

    if (bid < 256) {
        // node projections: rows bid*4 .. bid*4+3
        const int row = bid * 4 + g;
        lds_buf[g][c] = h[row * INDIM + c];
        __syncthreads();
        float q = 0.f, k = 0.f, v = 0.f;
#pragma unroll
        for (int r = 0; r < INDIM; ++r) {
            const float hv = lds_buf[g][r];
            q = fmaf(hv, WQ[r * HD + c], q);
            k = fmaf(hv, WK[r * HD + c], k);
            v = fmaf(hv, WV[r * HD + c], v);
        }
        Qh[row * HD + c] = q;
        Kh[row * HD + c] = k;
        Vh[row * HD + c] = v;
    } else if (bid < 320) {
        // dedup: last edge with a given (src,dst) wins (numpy scatter-set semantics)
        const int k = (bid - 256) * 256 + tid;          // 0..16383
        atomicMax(&winner[src[k] * NN + dst[k]], k + 1);
    } else {
        // partial column sums of h: chunk p = 64 rows
        const int p = bid - 320;                        // 0..15
        float s = 0.f;
        const int j0 = p * 64 + g * 16;
        for (int j = j0; j < j0 + 16; ++j) s += h[j * INDIM + c];
        lds_buf[g][c] = s;
        __syncthreads();
        if (g == 0)
            Spart[p * INDIM + c] = lds_buf[0][c] + lds_buf[1][c] + lds_buf[2][c] + lds_buf[3][c];
    }
}

// ---- Kernel B: per-edge delta + scatter accumulate (8 edges per wave) ----
__global__ __launch_bounds__(256)
void edge_kernel(const float* __restrict__ e,
                 const float* __restrict__ WE,
                 const float* __restrict__ Qh,
                 const float* __restrict__ Kh,
                 const float* __restrict__ Vh,
                 const int*   __restrict__ src,
                 const int*   __restrict__ dst,
                 const int*   __restrict__ winner,
                 float* __restrict__ outacc,
                 float* __restrict__ zacc)
{
    const int gtid = blockIdx.x * 256 + threadIdx.x;
    const int wave = gtid >> 6;                      // 0..2047
    const int t    = threadIdx.x & 63;               // lane = h*8+d
    const int k0   = wave * 8;

    float ev[8];
#pragma unroll
    for (int i = 0; i < 8; ++i) ev[i] = e[(k0 + i) * INDIM + t];
    float acc[8] = {0.f, 0.f, 0.f, 0.f, 0.f, 0.f, 0.f, 0.f};
    // Eh[k,t] = sum_r e[k,r]*WE[r,t]; one WE load feeds 8 edges via readlane broadcast
#pragma unroll
    for (int r = 0; r < INDIM; ++r) {
        const float w = WE[r * HD + t];
#pragma unroll
        for (int i = 0; i < 8; ++i)
            acc[i] = fmaf(bcast(ev[i], r), w, acc[i]);
    }
#pragma unroll
    for (int i = 0; i < 8; ++i) {
        const int k = k0 + i;
        const int s = src[k];
        const int d = dst[k];
        // wave-uniform skip: duplicate losers (last-set-wins) and self-loops
        if (winner[s * NN + d] != k + 1 || s == d) continue;
        float term = Kh[s * HD + t] * Qh[d * HD + t] * acc[i];
        term += __shfl_xor(term, 1, 64);
        term += __shfl_xor(term, 2, 64);
        term += __shfl_xor(term, 4, 64);
        const float wr    = fminf(fmaxf(term * INV_SCALE, -5.f), 5.f);
        const float delta = __expf(wr) * INV_1P1 - C_BASE;
        atomicAdd(&outacc[d * HD + t], delta * Vh[s * HD + t]);
        if ((t & 7) == 0) atomicAdd(&zacc[d * 8 + (t >> 3)], delta);
    }
}

// ---- Kernel C: out[j,t] = (C*(S[t]-Vh[j,t]) + outacc[j,t]) / (C*(N-1) + zacc[j,h] + 1e-6)
// S[t] = (sum_j h[j,:]) @ WV[:,t], assembled per block from Spart.
__global__ __launch_bounds__(256)
void finalize_kernel(const float* __restrict__ WV,
                     const float* __restrict__ Vh,
                     const float* __restrict__ Spart,
                     const float* __restrict__ outacc,
                     const float* __restrict__ zacc,
                     float* __restrict__ out)
{
    const int tid = threadIdx.x;
    __shared__ float sh_hsum[INDIM];
    __shared__ float sh_S[HD];
    if (tid < INDIM) {
        float hs = 0.f;
#pragma unroll
        for (int p = 0; p < 16; ++p) hs += Spart[p * INDIM + tid];
        sh_hsum[tid] = hs;
    }
    __syncthreads();
    if (tid < HD) {
        float s = 0.f;
#pragma unroll
        for (int r = 0; r < INDIM; ++r) s += sh_hsum[r] * WV[r * HD + tid];
        sh_S[tid] = s;
    }
    __syncthreads();
    const int idx = blockIdx.x * 256 + tid;          // 0..65535
    const int j = idx >> 6, t = idx & 63;
    const float z = C_BASE * 1023.f + zacc[j * 8 + (t >> 3)] + 1e-6f;
    out[idx] = fmaf(C_BASE, sh_S[t] - Vh[idx], outacc[idx]) / z;
}

extern "C" void kernel_launch(void* const* d_in, const int* in_sizes, int n_in,
                              void* d_out, int out_size, void* d_ws, size_t ws_size,
                              hipStream_t stream) {
    const float* h  = (const float*)d_in[0];
    const float* e  = (const float*)d_in[1];
    const float* WQ = (const float*)d_in[2];
    const float* WK = (const float*)d_in[3];
    const float* WE = (const float*)d_in[4];
    // d_in[5..7] = WQ2, WK2, WE2 — provably unused: fake weights are overwritten
    // at every real-edge position and equal GAMMA/(1+GAMMA) elsewhere.
    const float* WV = (const float*)d_in[8];
    const int* src  = (const int*)d_in[9];
    const int* dst  = (const int*)d_in[10];
    float* out = (float*)d_out;

    char* ws = (char*)d_ws;
    float* Qh     = (float*)(ws + (0    << 10));   // 256 KB
    float* Kh     = (float*)(ws + (256  << 10));   // 256 KB
    float* Vh     = (float*)(ws + (512  << 10));   // 256 KB
    float* Spart  = (float*)(ws + (768  << 10));   // 4 KB (plain stores, no zeroing)
    // zeroed region: outacc(256K) + zacc(32K) + winner(4M), contiguous
    float* outacc = (float*)(ws + (1024 << 10));
    float* zacc   = (float*)(ws + (1280 << 10));
    int*   winner = (int*)  (ws + (1312 << 10));
    const size_t zbytes = (288 << 10) + (4u << 20);

    hipMemsetAsync(outacc, 0, zbytes, stream);
    hipLaunchKernelGGL(prep_kernel, dim3(336), dim3(256), 0, stream,
                       h, WQ, WK, WV, src, dst, Qh, Kh, Vh, Spart, winner);
    hipLaunchKernelGGL(edge_kernel, dim3(512), dim3(256), 0, stream,
                       e, WE, Qh, Kh, Vh, src, dst, winner, outacc, zacc);
    hipLaunchKernelGGL(finalize_kernel, dim3(256), dim3(256), 0, stream,
                       WV, Vh, Spart, outacc, zacc, out);
}